// Round 6
// baseline (341.185 us; speedup 1.0000x reference)
//
#include <hip/hip_runtime.h>
#include <hip/hip_bf16.h>
#include <math.h>

// Mixer2dTriU: B=64, T=512, C=512, fp32 in/out.
// Pipeline:
//   memset(red); prep (conv_weights + ln_stats fused); ln1_norm_t;
//   gemm_mixer (256^2, fused ln2 stats); ln2_norm; gemm_d1; gemm_d2.
//
// GEMM mainloop (all three GEMMs): 256x256 tile, BK=64, 512 threads = 8 waves
// (2 M x 4 N), SINGLE 64 KB LDS buffer (64 KB static is run-proven in r4),
// 8 K-iterations for the square GEMMs (halved from 16 -- measured invariant
// across r0/r1/r4 is a ~constant per-K-iteration stall regardless of
// schedule, so sequential iteration count is the lever under test).
// Per iteration (T14 async-STAGE split, race-free by construction):
//   issue next tile's 8 global dwordx4 -> regs; ds_read+MFMA current tile;
//   __syncthreads (vmcnt(0) drain lands AFTER compute; reg loads landed);
//   ds_write regs -> LDS; __syncthreads.
// Pure HIP, no inline asm.  LDS swizzle: canonical G4 family, phys chunk =
// logical ^ (row&7) -- bank partners 8 lanes apart (r1-proven-zero-conflict
// spacing).  T5 setprio around MFMA.  Bijective XCD swizzle; grid = 256
// blocks = exactly 1 per CU (no tail).

#define B_ 64
#define T_ 512
#define C_ 512
#define TC_ (T_ * C_)
static_assert(TC_ == 262144, "");

typedef __attribute__((ext_vector_type(8))) short bf16x8;
typedef __attribute__((ext_vector_type(4))) float f32x4;

__device__ __forceinline__ unsigned short f2bf(float f) {
  union { float f; unsigned u; } v; v.f = f;
  unsigned r = v.u + 0x7FFF + ((v.u >> 16) & 1);   // RNE
  return (unsigned short)(r >> 16);
}
__device__ __forceinline__ float bf2f(unsigned short h) {
  union { unsigned u; float f; } v; v.u = ((unsigned)h) << 16; return v.f;
}

// async global -> LDS, 16 B per lane (global_load_lds_dwordx4)
__device__ __forceinline__ void load16_lds(const void* gsrc, void* ldst) {
  __builtin_amdgcn_global_load_lds(
      (const __attribute__((address_space(1))) unsigned int*)gsrc,
      (__attribute__((address_space(3))) unsigned int*)ldst,
      16, 0, 0);
}

// ------------- prep: weight conversion + ln1 stats (fused, independent) -------------
__global__ __launch_bounds__(256) void prep(
    const float* __restrict__ triM, const float* __restrict__ d1w,
    const float* __restrict__ d2w, unsigned short* __restrict__ Mb,
    unsigned short* __restrict__ W1b, unsigned short* __restrict__ W2b,
    const float* __restrict__ x, float* __restrict__ red) {
  if (blockIdx.x < 1024) {
    // weight conversion: tril(M), W1, W2 -> bf16
    const int idx = blockIdx.x * 256 + threadIdx.x;   // 262144 total
    const int i = idx >> 9, j = idx & 511;
    Mb[idx]  = (j <= i) ? f2bf(triM[idx]) : (unsigned short)0;
    W1b[idx] = f2bf(d1w[idx]);
    W2b[idx] = f2bf(d2w[idx]);
    return;
  }
  // ln1 stats: per-batch sum / sumsq, split-16, atomicAdd
  const int bb = blockIdx.x - 1024;
  const int b = bb >> 4;
  const int s = bb & 15;
  const float4* p = (const float4*)(x + (size_t)b * TC_) + (size_t)s * 4096;
  float s1 = 0.f, s2 = 0.f;
  for (int i = threadIdx.x; i < 4096; i += 256) {
    float4 v = p[i];
    s1 += v.x + v.y + v.z + v.w;
    s2 += v.x * v.x + v.y * v.y + v.z * v.z + v.w * v.w;
  }
#pragma unroll
  for (int o = 32; o; o >>= 1) { s1 += __shfl_down(s1, o, 64); s2 += __shfl_down(s2, o, 64); }
  __shared__ float sm[8];
  const int w = threadIdx.x >> 6, lane = threadIdx.x & 63;
  if (lane == 0) { sm[w * 2] = s1; sm[w * 2 + 1] = s2; }
  __syncthreads();
  if (threadIdx.x == 0) {
    float a = 0.f, c = 0.f;
    for (int i = 0; i < 4; ++i) { a += sm[2 * i]; c += sm[2 * i + 1]; }
    atomicAdd(&red[b * 2], a);
    atomicAdd(&red[b * 2 + 1], c);
  }
}

// ------------- ln1 normalize + transposed bf16 write -------------
__global__ __launch_bounds__(256) void ln1_norm_t(
    const float* __restrict__ x, const float* __restrict__ w,
    const float* __restrict__ bvec, const float* __restrict__ red1,
    unsigned short* __restrict__ XnT) {
  __shared__ unsigned short tile[64][65];
  const int b = blockIdx.z;
  const int t0 = blockIdx.y * 64;
  const int c0 = blockIdx.x * 64;
  const float mu = red1[b * 2] * (1.f / TC_);
  const float rstd = rsqrtf(red1[b * 2 + 1] * (1.f / TC_) - mu * mu + 1e-5f);
  const int tid = threadIdx.x;
  const int r = tid >> 4;            // 0..15
  const int cg = (tid & 15) * 4;     // 0..60
#pragma unroll
  for (int rr = 0; rr < 4; ++rr) {
    const int t = t0 + rr * 16 + r;
    const float4 xv = *(const float4*)&x[((size_t)b * T_ + t) * C_ + c0 + cg];
    const float4 wv = *(const float4*)&w[(size_t)t * C_ + c0 + cg];
    const float4 bv = *(const float4*)&bvec[(size_t)t * C_ + c0 + cg];
    tile[rr * 16 + r][cg + 0] = f2bf((xv.x - mu) * rstd * wv.x + bv.x);
    tile[rr * 16 + r][cg + 1] = f2bf((xv.y - mu) * rstd * wv.y + bv.y);
    tile[rr * 16 + r][cg + 2] = f2bf((xv.z - mu) * rstd * wv.z + bv.z);
    tile[rr * 16 + r][cg + 3] = f2bf((xv.w - mu) * rstd * wv.w + bv.w);
  }
  __syncthreads();
  const int cl = tid >> 2;           // 0..63
  const int tg = (tid & 3) * 16;     // 0,16,32,48
  alignas(16) unsigned short tmp[16];
#pragma unroll
  for (int j = 0; j < 16; ++j) tmp[j] = tile[tg + j][cl];
  unsigned short* o = &XnT[((size_t)b * C_ + c0 + cl) * T_ + t0 + tg];
  *(uint4*)&o[0] = *(const uint4*)&tmp[0];
  *(uint4*)&o[8] = *(const uint4*)&tmp[8];
}

// ============ 256x256 GEMM mainloop (8 waves, BK=64, reg-prefetch) ============
// A rows = C rows (at i0), B rows = C cols (at n0); both ld = 512 shorts.
// LDS tile [256 rows][64 shorts = 8 chunks of 16B], single buffer per operand.
// Physical chunk p of row holds logical chunk p ^ (row & 7); fragment-read
// bank partners are lanes (m16, m16+8) -- the proven-conflict-free spacing.
__device__ __forceinline__ void gemm_mainloop256(
    const unsigned short* __restrict__ Ag, const unsigned short* __restrict__ Bg,
    int ktiles, unsigned short* As, unsigned short* Bs, f32x4 acc[8][4], int tid) {
  const int lane = tid & 63, w = tid >> 6;
  const int wm = w >> 2, wn = w & 3;            // 2 x 4 wave grid
  const int m16 = lane & 15, quad = lane >> 4;
  const int arow = (wm * 128 + m16) * 64;       // shorts (row stride 64)
  const int brow = (wn * 64 + m16) * 64;
  const int xk = m16 & 7;                       // read-side xor key
  // stage geometry: 2048 16B-chunks per operand tile = 512 thr x 4
  int rowc[4], lc[4];
#pragma unroll
  for (int j = 0; j < 4; ++j) {
    const int c = tid + 512 * j;
    rowc[j] = c >> 3;
    lc[j] = ((c & 7) ^ (rowc[j] & 7)) * 8;      // logical k-offset (shorts)
  }
  // prologue: tile 0 via global_load_lds (linear LDS dest, pre-swizzled src)
#pragma unroll
  for (int j = 0; j < 4; ++j) {
    const int c = tid + 512 * j;
    load16_lds(Ag + ((size_t)rowc[j] << 9) + lc[j], As + c * 8);
    load16_lds(Bg + ((size_t)rowc[j] << 9) + lc[j], Bs + c * 8);
  }
  __syncthreads();
  uint4 rA[4], rB[4];
  for (int T = 0; T < ktiles; ++T) {
    const int k1 = (T + 1) * 64;
    if (T + 1 < ktiles) {                       // issue next-tile loads -> regs
#pragma unroll
      for (int j = 0; j < 4; ++j) {
        rA[j] = *(const uint4*)(Ag + ((size_t)rowc[j] << 9) + k1 + lc[j]);
        rB[j] = *(const uint4*)(Bg + ((size_t)rowc[j] << 9) + k1 + lc[j]);
      }
    }
    // compute current tile: 2 k-slices x (8 M x 4 N) 16x16x32
#pragma unroll
    for (int ks = 0; ks < 2; ++ks) {
      const int co = (((ks * 4 + quad) ^ xk) * 8);
      bf16x8 af[8], bfr[4];
#pragma unroll
      for (int m = 0; m < 8; ++m)
        af[m] = *(const bf16x8*)&As[arow + m * 1024 + co];
#pragma unroll
      for (int n = 0; n < 4; ++n)
        bfr[n] = *(const bf16x8*)&Bs[brow + n * 1024 + co];
      __builtin_amdgcn_s_setprio(1);
#pragma unroll
      for (int m = 0; m < 8; ++m)
#pragma unroll
        for (int n = 0; n < 4; ++n)
          acc[m][n] = __builtin_amdgcn_mfma_f32_16x16x32_bf16(af[m], bfr[n], acc[m][n], 0, 0, 0);
      __builtin_amdgcn_s_setprio(0);
    }
    __syncthreads();          // all LDS reads done; reg loads have landed
    if (T + 1 < ktiles) {     // write next tile (swizzled position = linear c)
#pragma unroll
      for (int j = 0; j < 4; ++j) {
        const int c = tid + 512 * j;
        *(uint4*)(As + c * 8) = rA[j];
        *(uint4*)(Bs + c * 8) = rB[j];
      }
    }
    __syncthreads();          // writes visible before next tile's reads
  }
}

// bijective XCD swizzle for 256 blocks (256 % 8 == 0): each XCD gets a
// contiguous range of 32 logical tiles.
__device__ __forceinline__ int xcd_swizzle_256(int bid) {
  return ((bid & 7) << 5) | (bid >> 3);
}

// ---------------- mixer GEMM: Z = tril(M)@Xn + tri_b + inputs ----------------
__global__ __launch_bounds__(512, 2) void gemm_mixer(
    const unsigned short* __restrict__ Mb, const unsigned short* __restrict__ XnT,
    const float* __restrict__ trib, const float* __restrict__ inp,
    unsigned short* __restrict__ Z, float* __restrict__ red2) {
  __shared__ __align__(16) unsigned short lds[32768];   // 64 KB exactly
  const int swz = xcd_swizzle_256((int)blockIdx.x);
  const int b = swz >> 2;
  const int i0 = ((swz >> 1) & 1) * 256;
  const int c0 = (swz & 1) * 256;
  f32x4 acc[8][4];
#pragma unroll
  for (int m = 0; m < 8; ++m)
#pragma unroll
    for (int n = 0; n < 4; ++n) acc[m][n] = (f32x4){0.f, 0.f, 0.f, 0.f};
  // tril: rows < i0+256 only need k < i0+256
  gemm_mainloop256(Mb + (size_t)i0 * T_, XnT + (size_t)b * TC_ + (size_t)c0 * T_,
                   (i0 + 256) >> 6, lds, lds + 16384, acc, (int)threadIdx.x);
  const int tid = threadIdx.x, lane = tid & 63, w = tid >> 6;
  const int wm = w >> 2, wn = w & 3, m16 = lane & 15, quad = lane >> 4;
  const int rbase = i0 + wm * 128, cbase = c0 + wn * 64;
  float s1 = 0.f, s2 = 0.f;
#pragma unroll
  for (int m = 0; m < 8; ++m) {
#pragma unroll
    for (int g = 0; g < 4; ++g) {
      const int i = rbase + m * 16 + quad * 4 + g;
      const float tb = trib[i];
      const float* inrow = &inp[((size_t)b * T_ + i) * C_];
      unsigned short* zrow = &Z[((size_t)b * T_ + i) * C_];
#pragma unroll
      for (int n = 0; n < 4; ++n) {
        const int ch = cbase + n * 16 + m16;
        const float v = acc[m][n][g] + tb + inrow[ch];
        zrow[ch] = f2bf(v);
        s1 += v; s2 += v * v;
      }
    }
  }
#pragma unroll
  for (int o = 32; o; o >>= 1) { s1 += __shfl_down(s1, o, 64); s2 += __shfl_down(s2, o, 64); }
  // reuse the (dead) GEMM LDS for the 8-wave reduction (mainloop ends with
  // __syncthreads, so reuse is safe)
  float* smf = (float*)lds;
  if (lane == 0) { smf[w * 2] = s1; smf[w * 2 + 1] = s2; }
  __syncthreads();
  if (tid == 0) {
    float a = 0.f, c2 = 0.f;
    for (int i = 0; i < 8; ++i) { a += smf[2 * i]; c2 += smf[2 * i + 1]; }
    atomicAdd(&red2[b * 2], a);
    atomicAdd(&red2[b * 2 + 1], c2);
  }
}

// ---------------- ln2 normalize ----------------
__global__ __launch_bounds__(256) void ln2_norm(
    const unsigned short* __restrict__ Z, const float* __restrict__ red2,
    const float* __restrict__ w, const float* __restrict__ bvec,
    unsigned short* __restrict__ X2) {
  const size_t e = ((size_t)blockIdx.x * 256 + threadIdx.x) * 8;
  const int b = (int)(e >> 18);
  const int tc = (int)(e & (TC_ - 1));
  const float mu = red2[b * 2] * (1.f / TC_);
  const float rstd = rsqrtf(red2[b * 2 + 1] * (1.f / TC_) - mu * mu + 1e-5f);
  uint4 zp = *(const uint4*)&Z[e];
  const unsigned short* zs = (const unsigned short*)&zp;
  alignas(16) float wv[8], bb[8];
  *(float4*)&wv[0] = *(const float4*)&w[tc];
  *(float4*)&wv[4] = *(const float4*)&w[tc + 4];
  *(float4*)&bb[0] = *(const float4*)&bvec[tc];
  *(float4*)&bb[4] = *(const float4*)&bvec[tc + 4];
  alignas(16) unsigned short o[8];
#pragma unroll
  for (int j = 0; j < 8; ++j)
    o[j] = f2bf((bf2f(zs[j]) - mu) * rstd * wv[j] + bb[j]);
  *(uint4*)&X2[e] = *(const uint4*)&o[0];
}

// ---------------- MLP GEMM 1: H = gelu(X2 @ W1^T + b1) ----------------
__global__ __launch_bounds__(512, 2) void gemm_d1(
    const unsigned short* __restrict__ X2, const unsigned short* __restrict__ W1b,
    const float* __restrict__ d1b, unsigned short* __restrict__ H) {
  __shared__ __align__(16) unsigned short lds[32768];
  const int swz = xcd_swizzle_256((int)blockIdx.x);
  const int n0 = (swz >> 7) * 256;        // 2 n-strips; XCD-contiguous share W1 strip
  const int i0 = (swz & 127) * 256;
  f32x4 acc[8][4];
#pragma unroll
  for (int m = 0; m < 8; ++m)
#pragma unroll
    for (int n = 0; n < 4; ++n) acc[m][n] = (f32x4){0.f, 0.f, 0.f, 0.f};
  gemm_mainloop256(X2 + (size_t)i0 * C_, W1b + (size_t)n0 * C_, 8, lds, lds + 16384,
                   acc, (int)threadIdx.x);
  const int tid = threadIdx.x, lane = tid & 63, w = tid >> 6;
  const int wm = w >> 2, wn = w & 3, m16 = lane & 15, quad = lane >> 4;
  const int rbase = i0 + wm * 128, cbase = n0 + wn * 64;
#pragma unroll
  for (int m = 0; m < 8; ++m) {
#pragma unroll
    for (int g = 0; g < 4; ++g) {
      const int row = rbase + m * 16 + quad * 4 + g;
#pragma unroll
      for (int n = 0; n < 4; ++n) {
        const int col = cbase + n * 16 + m16;
        const float v = acc[m][n][g] + d1b[col];
        const float gl = 0.5f * v * (1.0f + erff(v * 0.70710678118654752f));
        H[(size_t)row * C_ + col] = f2bf(gl);
      }
    }
  }
}

// ---------------- MLP GEMM 2: out = X2 + H @ W2^T + b2 ----------------
__global__ __launch_bounds__(512, 2) void gemm_d2(
    const unsigned short* __restrict__ H, const unsigned short* __restrict__ W2b,
    const float* __restrict__ d2b, const unsigned short* __restrict__ X2,
    float* __restrict__ out) {
  __shared__ __align__(16) unsigned short lds[32768];
  const int swz = xcd_swizzle_256((int)blockIdx.x);
  const int n0 = (swz >> 7) * 256;
  const int i0 = (swz & 127) * 256;
  f32x4 acc[8][4];
#pragma unroll
  for (int m = 0; m < 8; ++m)
#pragma unroll
    for (int n = 0; n < 4; ++n) acc[m][n] = (f32x4){0.f, 0.f, 0.f, 0.f};
  gemm_mainloop256(H + (size_t)i0 * C_, W2b + (size_t)n0 * C_, 8, lds, lds + 16384,
                   acc, (int)threadIdx.x);
  const int tid = threadIdx.x, lane = tid & 63, w = tid >> 6;
  const int wm = w >> 2, wn = w & 3, m16 = lane & 15, quad = lane >> 4;
  const int rbase = i0 + wm * 128, cbase = n0 + wn * 64;
#pragma unroll
  for (int m = 0; m < 8; ++m) {
#pragma unroll
    for (int g = 0; g < 4; ++g) {
      const int row = rbase + m * 16 + quad * 4 + g;
#pragma unroll
      for (int n = 0; n < 4; ++n) {
        const int col = cbase + n * 16 + m16;
        out[(size_t)row * C_ + col] =
            acc[m][n][g] + d2b[col] + bf2f(X2[(size_t)row * C_ + col]);
      }
    }
  }
}

extern "C" void kernel_launch(void* const* d_in, const int* in_sizes, int n_in,
                              void* d_out, int out_size, void* d_ws, size_t ws_size,
                              hipStream_t stream) {
  const float* inp  = (const float*)d_in[0];
  const float* ln1w = (const float*)d_in[1];
  const float* ln1b = (const float*)d_in[2];
  const float* ln2w = (const float*)d_in[3];
  const float* ln2b = (const float*)d_in[4];
  const float* triM = (const float*)d_in[5];
  const float* trib = (const float*)d_in[6];
  const float* d1w  = (const float*)d_in[7];
  const float* d1b  = (const float*)d_in[8];
  const float* d2w  = (const float*)d_in[9];
  const float* d2b  = (const float*)d_in[10];
  float* out = (float*)d_out;

  char* ws = (char*)d_ws;
  float* red1 = (float*)ws;                         // 64*2 floats
  float* red2 = (float*)(ws + 512);                 // 64*2 floats
  unsigned short* Mb  = (unsigned short*)(ws + 1024);
  unsigned short* W1b = Mb + TC_;
  unsigned short* W2b = W1b + TC_;
  unsigned short* XnT = W2b + TC_;                  // [B][C][T] bf16
  unsigned short* Z   = XnT + (size_t)B_ * TC_;     // [B][T][C] bf16
  unsigned short* X2  = Z + (size_t)B_ * TC_;       // [B][T][C] bf16
  unsigned short* H   = X2 + (size_t)B_ * TC_;      // [B*T][C] bf16

  hipMemsetAsync(ws, 0, 1024, stream);
  prep<<<2048, 256, 0, stream>>>(triM, d1w, d2w, Mb, W1b, W2b, inp, red1);
  ln1_norm_t<<<dim3(8, 8, B_), 256, 0, stream>>>(inp, ln1w, ln1b, red1, XnT);
  gemm_mixer<<<256, 512, 0, stream>>>(Mb, XnT, trib, inp, Z, red2);
  ln2_norm<<<8192, 256, 0, stream>>>(Z, red2, ln2w, ln2b, X2);
  gemm_d1<<<256, 512, 0, stream>>>(X2, W1b, d1b, H);
  gemm_d2<<<256, 512, 0, stream>>>(H, W2b, d2b, X2, out);
}

// Round 7
// 261.117 us; speedup vs baseline: 1.3066x; 1.3066x over previous
//
#include <hip/hip_runtime.h>
#include <hip/hip_bf16.h>
#include <math.h>

// Mixer2dTriU: B=64, T=512, C=512, fp32 in/out.
// Pipeline:
//   memset(red); prep (conv_weights + ln_stats fused); ln1_norm_t;
//   gemm_mixer (fused ln2 stats); ln2_norm; gemm_d1; gemm_d2.
//
// GEMM (all three): 128x128 tile, BK=32, 512 threads = 8 waves (2M x 4N,
// per-wave 64x32 -> acc[4][2] = 32 f32/lane), 32 KB double-buffered LDS,
// __launch_bounds__(512,4): VGPR capped at 128 (no spills -- r6's reg-prefetch
// spilled 107 MB/dispatch) and 4 waves/SIMD -> 16 waves/CU = 50% occupancy,
// 2 resident blocks/CU hiding each other's barrier/latency stalls (the m97
// implicit-overlap mechanism; all prior rounds sat at ~20% occupancy).
// T3-minimal loop (r4-proven): stage next tile into other LDS buffer via
// global_load_lds, MFMA current, ONE __syncthreads (vmcnt drain after
// compute).  Chunk swizzle: r1-proven-zero-conflict key (row>>1)&3 applied
// global-source-side + read-side, linear LDS dest (rule #21).
// Bijective XCD swizzle over 1024 blocks; T5 setprio around MFMA.

#define B_ 64
#define T_ 512
#define C_ 512
#define TC_ (T_ * C_)
static_assert(TC_ == 262144, "");

typedef __attribute__((ext_vector_type(8))) short bf16x8;
typedef __attribute__((ext_vector_type(4))) float f32x4;

__device__ __forceinline__ unsigned short f2bf(float f) {
  union { float f; unsigned u; } v; v.f = f;
  unsigned r = v.u + 0x7FFF + ((v.u >> 16) & 1);   // RNE
  return (unsigned short)(r >> 16);
}
__device__ __forceinline__ float bf2f(unsigned short h) {
  union { unsigned u; float f; } v; v.u = ((unsigned)h) << 16; return v.f;
}

// async global -> LDS, 16 B per lane (global_load_lds_dwordx4)
__device__ __forceinline__ void load16_lds(const void* gsrc, void* ldst) {
  __builtin_amdgcn_global_load_lds(
      (const __attribute__((address_space(1))) unsigned int*)gsrc,
      (__attribute__((address_space(3))) unsigned int*)ldst,
      16, 0, 0);
}

// ------------- prep: weight conversion + ln1 stats (fused, independent) -------------
__global__ __launch_bounds__(256) void prep(
    const float* __restrict__ triM, const float* __restrict__ d1w,
    const float* __restrict__ d2w, unsigned short* __restrict__ Mb,
    unsigned short* __restrict__ W1b, unsigned short* __restrict__ W2b,
    const float* __restrict__ x, float* __restrict__ red) {
  if (blockIdx.x < 1024) {
    const int idx = blockIdx.x * 256 + threadIdx.x;   // 262144 total
    const int i = idx >> 9, j = idx & 511;
    Mb[idx]  = (j <= i) ? f2bf(triM[idx]) : (unsigned short)0;
    W1b[idx] = f2bf(d1w[idx]);
    W2b[idx] = f2bf(d2w[idx]);
    return;
  }
  const int bb = blockIdx.x - 1024;
  const int b = bb >> 4;
  const int s = bb & 15;
  const float4* p = (const float4*)(x + (size_t)b * TC_) + (size_t)s * 4096;
  float s1 = 0.f, s2 = 0.f;
  for (int i = threadIdx.x; i < 4096; i += 256) {
    float4 v = p[i];
    s1 += v.x + v.y + v.z + v.w;
    s2 += v.x * v.x + v.y * v.y + v.z * v.z + v.w * v.w;
  }
#pragma unroll
  for (int o = 32; o; o >>= 1) { s1 += __shfl_down(s1, o, 64); s2 += __shfl_down(s2, o, 64); }
  __shared__ float sm[8];
  const int w = threadIdx.x >> 6, lane = threadIdx.x & 63;
  if (lane == 0) { sm[w * 2] = s1; sm[w * 2 + 1] = s2; }
  __syncthreads();
  if (threadIdx.x == 0) {
    float a = 0.f, c = 0.f;
    for (int i = 0; i < 4; ++i) { a += sm[2 * i]; c += sm[2 * i + 1]; }
    atomicAdd(&red[b * 2], a);
    atomicAdd(&red[b * 2 + 1], c);
  }
}

// ------------- ln1 normalize + transposed bf16 write -------------
__global__ __launch_bounds__(256) void ln1_norm_t(
    const float* __restrict__ x, const float* __restrict__ w,
    const float* __restrict__ bvec, const float* __restrict__ red1,
    unsigned short* __restrict__ XnT) {
  __shared__ unsigned short tile[64][65];
  const int b = blockIdx.z;
  const int t0 = blockIdx.y * 64;
  const int c0 = blockIdx.x * 64;
  const float mu = red1[b * 2] * (1.f / TC_);
  const float rstd = rsqrtf(red1[b * 2 + 1] * (1.f / TC_) - mu * mu + 1e-5f);
  const int tid = threadIdx.x;
  const int r = tid >> 4;            // 0..15
  const int cg = (tid & 15) * 4;     // 0..60
#pragma unroll
  for (int rr = 0; rr < 4; ++rr) {
    const int t = t0 + rr * 16 + r;
    const float4 xv = *(const float4*)&x[((size_t)b * T_ + t) * C_ + c0 + cg];
    const float4 wv = *(const float4*)&w[(size_t)t * C_ + c0 + cg];
    const float4 bv = *(const float4*)&bvec[(size_t)t * C_ + c0 + cg];
    tile[rr * 16 + r][cg + 0] = f2bf((xv.x - mu) * rstd * wv.x + bv.x);
    tile[rr * 16 + r][cg + 1] = f2bf((xv.y - mu) * rstd * wv.y + bv.y);
    tile[rr * 16 + r][cg + 2] = f2bf((xv.z - mu) * rstd * wv.z + bv.z);
    tile[rr * 16 + r][cg + 3] = f2bf((xv.w - mu) * rstd * wv.w + bv.w);
  }
  __syncthreads();
  const int cl = tid >> 2;           // 0..63
  const int tg = (tid & 3) * 16;     // 0,16,32,48
  alignas(16) unsigned short tmp[16];
#pragma unroll
  for (int j = 0; j < 16; ++j) tmp[j] = tile[tg + j][cl];
  unsigned short* o = &XnT[((size_t)b * C_ + c0 + cl) * T_ + t0 + tg];
  *(uint4*)&o[0] = *(const uint4*)&tmp[0];
  *(uint4*)&o[8] = *(const uint4*)&tmp[8];
}

// ============ 128x128 GEMM mainloop (8 waves, BK=32, 32 KB dbuf) ============
// A rows = C rows (at i0), B rows = C cols (at n0); both ld = 512 shorts.
// LDS tile [128 rows][32 shorts]; 4 chunks of 16 B per row.  Physical chunk
// p of row holds logical chunk p ^ ((row>>1)&3) (r1-measured: 0 conflicts).
// Stage: linear LDS dest, inverse-permuted global source (involution).
__device__ __forceinline__ void stage_tile128(
    const unsigned short* __restrict__ Ag, const unsigned short* __restrict__ Bg,
    int k0, unsigned short* As, unsigned short* Bs, int tid) {
  // 512 chunks per operand, 512 threads: one A chunk + one B chunk each
  const int row = tid >> 2;
  const int l = ((tid & 3) ^ ((row >> 1) & 3)) * 8;    // swizzled k-off (shorts)
  load16_lds(Ag + ((size_t)row << 9) + k0 + l, As + tid * 8);
  load16_lds(Bg + ((size_t)row << 9) + k0 + l, Bs + tid * 8);
}

// one K-tile of MFMA: 4 M x 2 N 16x16x32 per wave
__device__ __forceinline__ void mfma_tile128(
    const unsigned short* __restrict__ As, const unsigned short* __restrict__ Bs,
    int arow, int brow, int co, f32x4 acc[4][2]) {
  bf16x8 af[4], bfr[2];
#pragma unroll
  for (int m = 0; m < 4; ++m)
    af[m] = *(const bf16x8*)&As[arow + m * 512 + co];
#pragma unroll
  for (int n = 0; n < 2; ++n)
    bfr[n] = *(const bf16x8*)&Bs[brow + n * 512 + co];
  __builtin_amdgcn_s_setprio(1);
#pragma unroll
  for (int m = 0; m < 4; ++m)
#pragma unroll
    for (int n = 0; n < 2; ++n)
      acc[m][n] = __builtin_amdgcn_mfma_f32_16x16x32_bf16(af[m], bfr[n], acc[m][n], 0, 0, 0);
  __builtin_amdgcn_s_setprio(0);
}

__device__ __forceinline__ void gemm_mainloop128(
    const unsigned short* __restrict__ Ag, const unsigned short* __restrict__ Bg,
    int ktiles,                               // even (4..16)
    unsigned short* lds, f32x4 acc[4][2], int tid) {
  const int lane = tid & 63;
  const int w = tid >> 6;
  const int wm = w >> 2, wn = w & 3;          // 2 x 4 wave grid
  const int m16 = lane & 15, quad = lane >> 4;
  unsigned short* A0 = lds;                   // 8 KB each
  unsigned short* B0 = lds + 4096;
  unsigned short* A1 = lds + 8192;
  unsigned short* B1 = lds + 12288;
  const int arow = (wm * 64 + m16) * 32;      // shorts (row stride 32)
  const int brow = (wn * 32 + m16) * 32;
  const int co = (quad ^ ((m16 >> 1) & 3)) * 8;   // read-side xor (r1-proven)
  stage_tile128(Ag, Bg, 0, A0, B0, tid);      // prologue: tile 0
  __syncthreads();
  for (int kt = 0; kt < ktiles; kt += 2) {
    // even: prefetch kt+1 -> (A1,B1), compute (A0,B0), drain after MFMA
    stage_tile128(Ag, Bg, (kt + 1) * 32, A1, B1, tid);
    mfma_tile128(A0, B0, arow, brow, co, acc);
    __syncthreads();
    // odd: prefetch kt+2 -> (A0,B0), compute (A1,B1)
    if (kt + 2 < ktiles)
      stage_tile128(Ag, Bg, (kt + 2) * 32, A0, B0, tid);
    mfma_tile128(A1, B1, arow, brow, co, acc);
    __syncthreads();
  }
}

// bijective XCD swizzle for 1024 blocks (1024 % 8 == 0)
__device__ __forceinline__ int xcd_swizzle_1024(int bid) {
  return ((bid & 7) << 7) | (bid >> 3);
}

// ---------------- mixer GEMM: Z = tril(M)@Xn + tri_b + inputs ----------------
__global__ __launch_bounds__(512, 4) void gemm_mixer(
    const unsigned short* __restrict__ Mb, const unsigned short* __restrict__ XnT,
    const float* __restrict__ trib, const float* __restrict__ inp,
    unsigned short* __restrict__ Z, float* __restrict__ red2) {
  __shared__ __align__(16) unsigned short lds[16384];   // 32 KB
  const int swz = xcd_swizzle_1024((int)blockIdx.x);
  const int b = swz >> 4;
  const int i0 = ((swz >> 2) & 3) * 128;
  const int c0 = (swz & 3) * 128;
  f32x4 acc[4][2];
#pragma unroll
  for (int m = 0; m < 4; ++m)
#pragma unroll
    for (int n = 0; n < 2; ++n) acc[m][n] = (f32x4){0.f, 0.f, 0.f, 0.f};
  // tril: rows < i0+128 only need k < i0+128
  gemm_mainloop128(Mb + (size_t)i0 * T_, XnT + (size_t)b * TC_ + (size_t)c0 * T_,
                   (i0 >> 5) + 4, lds, acc, (int)threadIdx.x);
  const int tid = threadIdx.x, lane = tid & 63, w = tid >> 6;
  const int wm = w >> 2, wn = w & 3, m16 = lane & 15, quad = lane >> 4;
  const int rbase = i0 + wm * 64, cbase = c0 + wn * 32;
  float s1 = 0.f, s2 = 0.f;
#pragma unroll
  for (int m = 0; m < 4; ++m) {
#pragma unroll
    for (int g = 0; g < 4; ++g) {
      const int i = rbase + m * 16 + quad * 4 + g;
      const float tb = trib[i];
      const float* inrow = &inp[((size_t)b * T_ + i) * C_];
      unsigned short* zrow = &Z[((size_t)b * T_ + i) * C_];
#pragma unroll
      for (int n = 0; n < 2; ++n) {
        const int ch = cbase + n * 16 + m16;
        const float v = acc[m][n][g] + tb + inrow[ch];
        zrow[ch] = f2bf(v);
        s1 += v; s2 += v * v;
      }
    }
  }
#pragma unroll
  for (int o = 32; o; o >>= 1) { s1 += __shfl_down(s1, o, 64); s2 += __shfl_down(s2, o, 64); }
  __shared__ float smf[16];
  if (lane == 0) { smf[w * 2] = s1; smf[w * 2 + 1] = s2; }
  __syncthreads();
  if (tid == 0) {
    float a = 0.f, c2 = 0.f;
    for (int i = 0; i < 8; ++i) { a += smf[2 * i]; c2 += smf[2 * i + 1]; }
    atomicAdd(&red2[b * 2], a);
    atomicAdd(&red2[b * 2 + 1], c2);
  }
}

// ---------------- ln2 normalize ----------------
__global__ __launch_bounds__(256) void ln2_norm(
    const unsigned short* __restrict__ Z, const float* __restrict__ red2,
    const float* __restrict__ w, const float* __restrict__ bvec,
    unsigned short* __restrict__ X2) {
  const size_t e = ((size_t)blockIdx.x * 256 + threadIdx.x) * 8;
  const int b = (int)(e >> 18);
  const int tc = (int)(e & (TC_ - 1));
  const float mu = red2[b * 2] * (1.f / TC_);
  const float rstd = rsqrtf(red2[b * 2 + 1] * (1.f / TC_) - mu * mu + 1e-5f);
  uint4 zp = *(const uint4*)&Z[e];
  const unsigned short* zs = (const unsigned short*)&zp;
  alignas(16) float wv[8], bb[8];
  *(float4*)&wv[0] = *(const float4*)&w[tc];
  *(float4*)&wv[4] = *(const float4*)&w[tc + 4];
  *(float4*)&bb[0] = *(const float4*)&bvec[tc];
  *(float4*)&bb[4] = *(const float4*)&bvec[tc + 4];
  alignas(16) unsigned short o[8];
#pragma unroll
  for (int j = 0; j < 8; ++j)
    o[j] = f2bf((bf2f(zs[j]) - mu) * rstd * wv[j] + bb[j]);
  *(uint4*)&X2[e] = *(const uint4*)&o[0];
}

// ---------------- MLP GEMM 1: H = gelu(X2 @ W1^T + b1) ----------------
__global__ __launch_bounds__(512, 4) void gemm_d1(
    const unsigned short* __restrict__ X2, const unsigned short* __restrict__ W1b,
    const float* __restrict__ d1b, unsigned short* __restrict__ H) {
  __shared__ __align__(16) unsigned short lds[16384];
  const int swz = xcd_swizzle_1024((int)blockIdx.x);
  const int i0 = (swz & 255) * 128;     // 256 M-tiles; consecutive swz share n0
  const int n0 = (swz >> 8) * 128;      // 4 N-tiles (W panel hot in XCD L2)
  f32x4 acc[4][2];
#pragma unroll
  for (int m = 0; m < 4; ++m)
#pragma unroll
    for (int n = 0; n < 2; ++n) acc[m][n] = (f32x4){0.f, 0.f, 0.f, 0.f};
  gemm_mainloop128(X2 + (size_t)i0 * C_, W1b + (size_t)n0 * C_, 16, lds, acc,
                   (int)threadIdx.x);
  const int tid = threadIdx.x, lane = tid & 63, w = tid >> 6;
  const int wm = w >> 2, wn = w & 3, m16 = lane & 15, quad = lane >> 4;
  const int rbase = i0 + wm * 64, cbase = n0 + wn * 32;
#pragma unroll
  for (int m = 0; m < 4; ++m) {
#pragma unroll
    for (int g = 0; g < 4; ++g) {
      const int row = rbase + m * 16 + quad * 4 + g;
#pragma unroll
      for (int n = 0; n < 2; ++n) {
        const int col = cbase + n * 16 + m16;
        const float v = acc[m][n][g] + d1b[col];
        const float gl = 0.5f * v * (1.0f + erff(v * 0.70710678118654752f));
        H[(size_t)row * C_ + col] = f2bf(gl);
      }
    }
  }
}

// ---------------- MLP GEMM 2: out = X2 + H @ W2^T + b2 ----------------
__global__ __launch_bounds__(512, 4) void gemm_d2(
    const unsigned short* __restrict__ H, const unsigned short* __restrict__ W2b,
    const float* __restrict__ d2b, const unsigned short* __restrict__ X2,
    float* __restrict__ out) {
  __shared__ __align__(16) unsigned short lds[16384];
  const int swz = xcd_swizzle_1024((int)blockIdx.x);
  const int i0 = (swz & 255) * 128;
  const int n0 = (swz >> 8) * 128;
  f32x4 acc[4][2];
#pragma unroll
  for (int m = 0; m < 4; ++m)
#pragma unroll
    for (int n = 0; n < 2; ++n) acc[m][n] = (f32x4){0.f, 0.f, 0.f, 0.f};
  gemm_mainloop128(H + (size_t)i0 * C_, W2b + (size_t)n0 * C_, 16, lds, acc,
                   (int)threadIdx.x);
  const int tid = threadIdx.x, lane = tid & 63, w = tid >> 6;
  const int wm = w >> 2, wn = w & 3, m16 = lane & 15, quad = lane >> 4;
  const int rbase = i0 + wm * 64, cbase = n0 + wn * 32;
#pragma unroll
  for (int m = 0; m < 4; ++m) {
#pragma unroll
    for (int g = 0; g < 4; ++g) {
      const int row = rbase + m * 16 + quad * 4 + g;
#pragma unroll
      for (int n = 0; n < 2; ++n) {
        const int col = cbase + n * 16 + m16;
        out[(size_t)row * C_ + col] =
            acc[m][n][g] + d2b[col] + bf2f(X2[(size_t)row * C_ + col]);
      }
    }
  }
}

extern "C" void kernel_launch(void* const* d_in, const int* in_sizes, int n_in,
                              void* d_out, int out_size, void* d_ws, size_t ws_size,
                              hipStream_t stream) {
  const float* inp  = (const float*)d_in[0];
  const float* ln1w = (const float*)d_in[1];
  const float* ln1b = (const float*)d_in[2];
  const float* ln2w = (const float*)d_in[3];
  const float* ln2b = (const float*)d_in[4];
  const float* triM = (const float*)d_in[5];
  const float* trib = (const float*)d_in[6];
  const float* d1w  = (const float*)d_in[7];
  const float* d1b  = (const float*)d_in[8];
  const float* d2w  = (const float*)d_in[9];
  const float* d2b  = (const float*)d_in[10];
  float* out = (float*)d_out;

  char* ws = (char*)d_ws;
  float* red1 = (float*)ws;                         // 64*2 floats
  float* red2 = (float*)(ws + 512);                 // 64*2 floats
  unsigned short* Mb  = (unsigned short*)(ws + 1024);
  unsigned short* W1b = Mb + TC_;
  unsigned short* W2b = W1b + TC_;
  unsigned short* XnT = W2b + TC_;                  // [B][C][T] bf16
  unsigned short* Z   = XnT + (size_t)B_ * TC_;     // [B][T][C] bf16
  unsigned short* X2  = Z + (size_t)B_ * TC_;       // [B][T][C] bf16
  unsigned short* H   = X2 + (size_t)B_ * TC_;      // [B*T][C] bf16

  hipMemsetAsync(ws, 0, 1024, stream);
  prep<<<2048, 256, 0, stream>>>(triM, d1w, d2w, Mb, W1b, W2b, inp, red1);
  ln1_norm_t<<<dim3(8, 8, B_), 256, 0, stream>>>(inp, ln1w, ln1b, red1, XnT);
  gemm_mixer<<<1024, 512, 0, stream>>>(Mb, XnT, trib, inp, Z, red2);
  ln2_norm<<<8192, 256, 0, stream>>>(Z, red2, ln2w, ln2b, X2);
  gemm_d1<<<1024, 512, 0, stream>>>(X2, W1b, d1b, H);
  gemm_d2<<<1024, 512, 0, stream>>>(H, W2b, d2b, X2, out);
}